// Round 1
// baseline (1548.372 us; speedup 1.0000x reference)
//
#include <hip/hip_runtime.h>
#include <math.h>

#define DDIM 512
#define BK 32
#define QT 64
#define MT 256
#define NTHREADS 256
#define KNN 5
#define BIGF 3.0e38f

// Sorted top-5 insert (ascending; s[4] = worst). All indices compile-time
// constant -> stays in registers (no scratch).
__device__ __forceinline__ void t5_insert(float (&s)[KNN], int (&ix)[KNN], float v, int vi) {
    if (v < s[4]) {
        s[4] = v; ix[4] = vi;
        if (s[4] < s[3]) { float t = s[3]; s[3] = s[4]; s[4] = t; int u = ix[3]; ix[3] = ix[4]; ix[4] = u; }
        if (s[3] < s[2]) { float t = s[2]; s[2] = s[3]; s[3] = t; int u = ix[2]; ix[2] = ix[3]; ix[3] = u; }
        if (s[2] < s[1]) { float t = s[1]; s[1] = s[2]; s[2] = t; int u = ix[1]; ix[1] = ix[2]; ix[2] = u; }
        if (s[1] < s[0]) { float t = s[0]; s[0] = s[1]; s[1] = t; int u = ix[0]; ix[0] = ix[1]; ix[1] = u; }
    }
}

union SMemA {
    struct { float a[BK][QT]; float b[BK][MT]; } stage;   // 8 KB + 32 KB
    struct { float red[MT][8]; float s[MT]; } sq;         // 9 KB (used after K-loop)
    struct { float s[QT][16][KNN]; int idx[QT][16][KNN]; } merge; // 40 KB (used last)
};

// Phase A: per (query-tile, 256-row chunk): score = ||m||^2 - 2 q.m, keep top-5
// per query, write 5 candidates per (chunk, query) to ws.
__global__ __launch_bounds__(NTHREADS, 2) void knn_partial(
        const float* __restrict__ emb, const float* __restrict__ mem,
        float2* __restrict__ cand, int N, int Q) {
    __shared__ SMemA sm;
    const int tid  = threadIdx.x;
    const int qg   = tid & 15;   // 16 query groups x 4 queries
    const int rg   = tid >> 4;   // 16 row groups x 16 rows
    const int col4 = tid & 7;    // staging: float4 column within 32-float K-slab
    const int rowb = tid >> 3;   // staging: base row (0..31)
    const int qbase = blockIdx.x * QT;
    const int mbase = blockIdx.y * MT;

    float acc[4][16];
#pragma unroll
    for (int q = 0; q < 4; ++q)
#pragma unroll
        for (int j = 0; j < 16; ++j) acc[q][j] = 0.f;
    float sqp[8] = {0.f, 0.f, 0.f, 0.f, 0.f, 0.f, 0.f, 0.f};

    for (int k0 = 0; k0 < DDIM; k0 += BK) {
        __syncthreads();
        // stage A (64q x 32k), k-major scatter
#pragma unroll
        for (int i = 0; i < 2; ++i) {
            int qrow = rowb + 32 * i;
            float4 v = *(const float4*)(emb + (size_t)(qbase + qrow) * DDIM + k0 + col4 * 4);
            sm.stage.a[col4 * 4 + 0][qrow] = v.x;
            sm.stage.a[col4 * 4 + 1][qrow] = v.y;
            sm.stage.a[col4 * 4 + 2][qrow] = v.z;
            sm.stage.a[col4 * 4 + 3][qrow] = v.w;
        }
        // stage B (256m x 32k), k-major scatter + ||m||^2 partials
#pragma unroll
        for (int i = 0; i < 8; ++i) {
            int mrow = rowb + 32 * i;
            int grow = mbase + mrow;
            float4 v = make_float4(0.f, 0.f, 0.f, 0.f);
            if (grow < N) v = *(const float4*)(mem + (size_t)grow * DDIM + k0 + col4 * 4);
            sm.stage.b[col4 * 4 + 0][mrow] = v.x;
            sm.stage.b[col4 * 4 + 1][mrow] = v.y;
            sm.stage.b[col4 * 4 + 2][mrow] = v.z;
            sm.stage.b[col4 * 4 + 3][mrow] = v.w;
            sqp[i] += v.x * v.x + v.y * v.y + v.z * v.z + v.w * v.w;
        }
        __syncthreads();
#pragma unroll 2
        for (int kk = 0; kk < BK; ++kk) {
            float av[4], bv[16];
            *(float4*)av        = *(const float4*)&sm.stage.a[kk][qg * 4];
            *(float4*)(bv + 0)  = *(const float4*)&sm.stage.b[kk][rg * 16 + 0];
            *(float4*)(bv + 4)  = *(const float4*)&sm.stage.b[kk][rg * 16 + 4];
            *(float4*)(bv + 8)  = *(const float4*)&sm.stage.b[kk][rg * 16 + 8];
            *(float4*)(bv + 12) = *(const float4*)&sm.stage.b[kk][rg * 16 + 12];
#pragma unroll
            for (int q = 0; q < 4; ++q)
#pragma unroll
                for (int j = 0; j < 16; ++j)
                    acc[q][j] = fmaf(av[q], bv[j], acc[q][j]);
        }
    }
    __syncthreads();
    // reduce ||m||^2 partials (8 threads per row)
#pragma unroll
    for (int i = 0; i < 8; ++i) sm.sq.red[rowb + 32 * i][col4] = sqp[i];
    __syncthreads();
    {
        float s = 0.f;
#pragma unroll
        for (int j = 0; j < 8; ++j) s += sm.sq.red[tid][j];
        sm.sq.s[tid] = s;
    }
    __syncthreads();
    // scores + per-thread top-5
    float t5s[4][KNN]; int t5i[4][KNN];
#pragma unroll
    for (int q = 0; q < 4; ++q)
#pragma unroll
        for (int c = 0; c < KNN; ++c) { t5s[q][c] = BIGF; t5i[q][c] = 0; }
#pragma unroll
    for (int j = 0; j < 16; ++j) {
        int m = rg * 16 + j;
        int grow = mbase + m;
        float sqm = sm.sq.s[m];
        if (grow < N) {
#pragma unroll
            for (int q = 0; q < 4; ++q) {
                float sc = fmaf(-2.f, acc[q][j], sqm);
                t5_insert(t5s[q], t5i[q], sc, grow);
            }
        }
    }
    __syncthreads();  // done reading sq.s; merge region may alias it
#pragma unroll
    for (int q = 0; q < 4; ++q)
#pragma unroll
        for (int c = 0; c < KNN; ++c) {
            sm.merge.s[qg * 4 + q][rg][c]   = t5s[q][c];
            sm.merge.idx[qg * 4 + q][rg][c] = t5i[q][c];
        }
    __syncthreads();
    if (tid < QT) {
        float fs[KNN] = {BIGF, BIGF, BIGF, BIGF, BIGF};
        int   fi[KNN] = {0, 0, 0, 0, 0};
        for (int r = 0; r < 16; ++r)
#pragma unroll
            for (int c = 0; c < KNN; ++c)
                t5_insert(fs, fi, sm.merge.s[tid][r][c], sm.merge.idx[tid][r][c]);
        size_t base = ((size_t)blockIdx.y * Q + (qbase + tid)) * KNN;
#pragma unroll
        for (int c = 0; c < KNN; ++c)
            cand[base + c] = make_float2(fs[c], __int_as_float(fi[c]));
    }
}

// Phase B: one wave per query: global top-5 from NC*5 candidates, gather the 5
// rows, exact f32 sqrt-distances, per-query sum.
__global__ void knn_merge_exact(const float* __restrict__ emb, const float* __restrict__ mem,
                                const float2* __restrict__ cand, float* __restrict__ qsum,
                                int Q, int NC) {
    const int q = blockIdx.x;
    const int lane = threadIdx.x;  // 64
    float fs[KNN] = {BIGF, BIGF, BIGF, BIGF, BIGF};
    int   fi[KNN] = {0, 0, 0, 0, 0};
    for (int c = lane; c < NC; c += 64) {
        const float2* p = cand + ((size_t)c * Q + q) * KNN;
#pragma unroll
        for (int k = 0; k < KNN; ++k) {
            float2 e = p[k];
            t5_insert(fs, fi, e.x, __float_as_int(e.y));
        }
    }
    __shared__ float2 ls[64][KNN];
    __shared__ int sel[KNN];
#pragma unroll
    for (int k = 0; k < KNN; ++k) ls[lane][k] = make_float2(fs[k], __int_as_float(fi[k]));
    __syncthreads();
    if (lane == 0) {
        float gs[KNN] = {BIGF, BIGF, BIGF, BIGF, BIGF};
        int   gi[KNN] = {0, 0, 0, 0, 0};
        for (int l = 0; l < 64; ++l)
#pragma unroll
            for (int k = 0; k < KNN; ++k)
                t5_insert(gs, gi, ls[l][k].x, __float_as_int(ls[l][k].y));
#pragma unroll
        for (int k = 0; k < KNN; ++k) sel[k] = gi[k];
    }
    __syncthreads();
    const float4* qp = (const float4*)(emb + (size_t)q * DDIM);
    float4 q0 = qp[lane * 2], q1 = qp[lane * 2 + 1];
    float ssum = 0.f;
    for (int k = 0; k < KNN; ++k) {
        const float4* mp = (const float4*)(mem + (size_t)sel[k] * DDIM);
        float4 m0 = mp[lane * 2], m1 = mp[lane * 2 + 1];
        float d0 = m0.x - q0.x, d1 = m0.y - q0.y, d2 = m0.z - q0.z, d3 = m0.w - q0.w;
        float d4 = m1.x - q1.x, d5 = m1.y - q1.y, d6 = m1.z - q1.z, d7 = m1.w - q1.w;
        float t = d0 * d0 + d1 * d1 + d2 * d2 + d3 * d3 + d4 * d4 + d5 * d5 + d6 * d6 + d7 * d7;
#pragma unroll
        for (int off = 32; off > 0; off >>= 1) t += __shfl_down(t, off);
        if (lane == 0) ssum += sqrtf(t);
    }
    if (lane == 0) qsum[q] = ssum;
}

// Phase C: deterministic final mean.
__global__ void knn_reduce(const float* __restrict__ qsum, float* __restrict__ out, int Q) {
    const int lane = threadIdx.x;
    float v = 0.f;
    for (int i = lane; i < Q; i += 64) v += qsum[i];
#pragma unroll
    for (int off = 32; off > 0; off >>= 1) v += __shfl_down(v, off);
    if (lane == 0) out[0] = v / (float)(Q * KNN);
}

extern "C" void kernel_launch(void* const* d_in, const int* in_sizes, int n_in,
                              void* d_out, int out_size, void* d_ws, size_t ws_size,
                              hipStream_t stream) {
    (void)n_in; (void)out_size; (void)ws_size;
    const float* emb = (const float*)d_in[0];
    const float* mem = (const float*)d_in[1];
    const int Q  = in_sizes[0] / DDIM;      // 256
    const int N  = in_sizes[1] / DDIM;      // 200000
    const int NC = (N + MT - 1) / MT;       // 782 chunks of 256 rows

    float2* cand = (float2*)d_ws;                                   // NC*Q*5 float2 (~8 MB)
    float*  qsum = (float*)((char*)d_ws + (size_t)NC * Q * KNN * sizeof(float2));

    dim3 gA(Q / QT, NC);  // qtile fast-varying -> 4 consecutive blocks share a chunk (L2 reuse)
    knn_partial<<<gA, NTHREADS, 0, stream>>>(emb, mem, cand, N, Q);
    knn_merge_exact<<<Q, 64, 0, stream>>>(emb, mem, cand, qsum, Q, NC);
    knn_reduce<<<1, 64, 0, stream>>>(qsum, (float*)d_out, Q);
}

// Round 2
// 496.584 us; speedup vs baseline: 3.1180x; 3.1180x over previous
//
#include <hip/hip_runtime.h>
#include <math.h>
#include <stdint.h>

#define DDIM 512
#define QN   256      // queries
#define MT   256      // memory rows per block (8 waves x 32)
#define WAVES 8
#define NT   (WAVES * 64)
#define KNN  5
#define BK   32
#define NSTEP (DDIM / BK)   // 16
#define BIGF 3.0e38f

typedef __attribute__((ext_vector_type(8))) short bf16x8;
typedef __attribute__((ext_vector_type(4))) float f32x4;

__device__ __forceinline__ unsigned short f2bf(float x) {
    union { float f; unsigned u; } c; c.f = x;
    unsigned r = c.u + 0x7FFFu + ((c.u >> 16) & 1u);   // RNE
    return (unsigned short)(r >> 16);
}

// Sorted top-5 insert (ascending; s[4] = worst). Static indices only.
__device__ __forceinline__ void t5_insert(float (&s)[KNN], int (&ix)[KNN], float v, int vi) {
    if (v < s[4]) {
        s[4] = v; ix[4] = vi;
        if (s[4] < s[3]) { float t = s[3]; s[3] = s[4]; s[4] = t; int u = ix[3]; ix[3] = ix[4]; ix[4] = u; }
        if (s[3] < s[2]) { float t = s[2]; s[2] = s[3]; s[3] = t; int u = ix[2]; ix[2] = ix[3]; ix[3] = u; }
        if (s[2] < s[1]) { float t = s[1]; s[1] = s[2]; s[2] = t; int u = ix[1]; ix[1] = ix[2]; ix[2] = u; }
        if (s[1] < s[0]) { float t = s[0]; s[0] = s[1]; s[1] = t; int u = ix[0]; ix[0] = ix[1]; ix[1] = u; }
    }
}

// Phase 0: queries f32 -> bf16 (tiny, L2-resident afterwards)
__global__ void conv_q(const float* __restrict__ emb, unsigned short* __restrict__ qbf) {
    int i = blockIdx.x * 256 + threadIdx.x;      // covers QN*DDIM/4 = 32768
    float4 v = ((const float4*)emb)[i];
    ushort4 o;
    o.x = f2bf(v.x); o.y = f2bf(v.y); o.z = f2bf(v.z); o.w = f2bf(v.w);
    ((ushort4*)qbf)[i] = o;
}

// Phase A: per 256-row chunk, scores = ||m||^2 - 2 q.m for ALL 256 queries via
// bf16 MFMA; memory read f32->reg exactly once; per-query top-5 -> cand.
__global__ __launch_bounds__(NT, 1) void knn_partial(
        const float* __restrict__ mem, const unsigned short* __restrict__ qbf,
        float2* __restrict__ cand, int N) {
    __shared__ union {
        unsigned short q[QN * BK];              // [256][32] bf16 row-major, 16 KB
        float2 merge[WAVES][QN][KNN];           // 80 KB (after K-loop)
    } smu;
    __shared__ float smsq[MT];

    const int tid  = threadIdx.x;
    const int lane = tid & 63;
    const int w    = tid >> 6;
    const int l15  = lane & 15;
    const int lq   = lane >> 4;                 // k-quarter 0..3
    const int chunk = blockIdx.x;
    const int rbase = chunk * MT + w * 32;

    int r0 = rbase + l15;      if (r0 >= N) r0 = N - 1;
    int r1 = rbase + 16 + l15; if (r1 >= N) r1 = N - 1;
    const float* pA0 = mem + (size_t)r0 * DDIM + lq * 8;
    const float* pA1 = mem + (size_t)r1 * DDIM + lq * 8;

    f32x4 acc[16][2];
    const f32x4 zero4 = {0.f, 0.f, 0.f, 0.f};
#pragma unroll
    for (int g = 0; g < 16; ++g) { acc[g][0] = zero4; acc[g][1] = zero4; }
    float sq0 = 0.f, sq1 = 0.f;

    for (int s = 0; s < NSTEP; ++s) {
        const int k0 = s * BK;
        // A: this wave's 32 memory rows, 8 contiguous f32 per lane per frag
        float4 a00 = *(const float4*)(pA0 + k0);
        float4 a01 = *(const float4*)(pA0 + k0 + 4);
        float4 a10 = *(const float4*)(pA1 + k0);
        float4 a11 = *(const float4*)(pA1 + k0 + 4);

        __syncthreads();   // previous step's q reads done
        // stage queries [256][32] bf16; thread covers two 16B pieces, lane-linear
#pragma unroll
        for (int p = 0; p < 2; ++p) {
            int e = p * 4096 + tid * 8;          // bf16 element index
            int row = e >> 5, col = e & 31;
            uint4 v = *(const uint4*)(qbf + (size_t)row * DDIM + k0 + col);
            *(uint4*)&smu.q[e] = v;
        }
        // convert A to bf16 frags + ||m||^2 partials (each element seen once)
        bf16x8 a0, a1;
        a0[0] = (short)f2bf(a00.x); a0[1] = (short)f2bf(a00.y);
        a0[2] = (short)f2bf(a00.z); a0[3] = (short)f2bf(a00.w);
        a0[4] = (short)f2bf(a01.x); a0[5] = (short)f2bf(a01.y);
        a0[6] = (short)f2bf(a01.z); a0[7] = (short)f2bf(a01.w);
        a1[0] = (short)f2bf(a10.x); a1[1] = (short)f2bf(a10.y);
        a1[2] = (short)f2bf(a10.z); a1[3] = (short)f2bf(a10.w);
        a1[4] = (short)f2bf(a11.x); a1[5] = (short)f2bf(a11.y);
        a1[6] = (short)f2bf(a11.z); a1[7] = (short)f2bf(a11.w);
        sq0 = fmaf(a00.x, a00.x, sq0); sq0 = fmaf(a00.y, a00.y, sq0);
        sq0 = fmaf(a00.z, a00.z, sq0); sq0 = fmaf(a00.w, a00.w, sq0);
        sq0 = fmaf(a01.x, a01.x, sq0); sq0 = fmaf(a01.y, a01.y, sq0);
        sq0 = fmaf(a01.z, a01.z, sq0); sq0 = fmaf(a01.w, a01.w, sq0);
        sq1 = fmaf(a10.x, a10.x, sq1); sq1 = fmaf(a10.y, a10.y, sq1);
        sq1 = fmaf(a10.z, a10.z, sq1); sq1 = fmaf(a10.w, a10.w, sq1);
        sq1 = fmaf(a11.x, a11.x, sq1); sq1 = fmaf(a11.y, a11.y, sq1);
        sq1 = fmaf(a11.z, a11.z, sq1); sq1 = fmaf(a11.w, a11.w, sq1);
        __syncthreads();   // staging visible

#pragma unroll
        for (int g = 0; g < 16; ++g) {
            bf16x8 b = *(const bf16x8*)&smu.q[(g * 16 + l15) * BK + lq * 8];
            acc[g][0] = __builtin_amdgcn_mfma_f32_16x16x32_bf16(a0, b, acc[g][0], 0, 0, 0);
            acc[g][1] = __builtin_amdgcn_mfma_f32_16x16x32_bf16(a1, b, acc[g][1], 0, 0, 0);
        }
    }

    // ||m||^2: reduce k-quarter partials across lanes sharing l15
    sq0 += __shfl_xor(sq0, 16); sq0 += __shfl_xor(sq0, 32);
    sq1 += __shfl_xor(sq1, 16); sq1 += __shfl_xor(sq1, 32);
    __syncthreads();           // last q reads done before merge-region reuse
    if (lane < 16) {
        smsq[w * 32 + lane]      = sq0;
        smsq[w * 32 + 16 + lane] = sq1;
    }
    __syncthreads();

    float rsq[8];
#pragma unroll
    for (int f = 0; f < 2; ++f)
#pragma unroll
        for (int e = 0; e < 4; ++e)
            rsq[f * 4 + e] = smsq[w * 32 + f * 16 + lq * 4 + e];

    // per query-group: scores -> per-lane top5 -> shfl merge -> LDS
#pragma unroll
    for (int g = 0; g < 16; ++g) {
        float ts[KNN] = {BIGF, BIGF, BIGF, BIGF, BIGF};
        int   ti[KNN] = {0, 0, 0, 0, 0};
#pragma unroll
        for (int f = 0; f < 2; ++f)
#pragma unroll
            for (int e = 0; e < 4; ++e) {
                int grow = rbase + f * 16 + lq * 4 + e;
                if (grow < N) {
                    float sc = fmaf(-2.f, acc[g][f][e], rsq[f * 4 + e]);
                    t5_insert(ts, ti, sc, grow);
                }
            }
#pragma unroll
        for (int x = 16; x <= 32; x <<= 1) {
            float os[KNN]; int oi[KNN];
#pragma unroll
            for (int c = 0; c < KNN; ++c) { os[c] = __shfl_xor(ts[c], x); oi[c] = __shfl_xor(ti[c], x); }
#pragma unroll
            for (int c = 0; c < KNN; ++c) t5_insert(ts, ti, os[c], oi[c]);
        }
        if (lane < 16) {
            int q = g * 16 + lane;
#pragma unroll
            for (int c = 0; c < KNN; ++c)
                smu.merge[w][q][c] = make_float2(ts[c], __int_as_float(ti[c]));
        }
    }
    __syncthreads();
    if (tid < QN) {
        float fs[KNN] = {BIGF, BIGF, BIGF, BIGF, BIGF};
        int   fi[KNN] = {0, 0, 0, 0, 0};
        for (int ww = 0; ww < WAVES; ++ww)
#pragma unroll
            for (int c = 0; c < KNN; ++c) {
                float2 e2 = smu.merge[ww][tid][c];
                t5_insert(fs, fi, e2.x, __float_as_int(e2.y));
            }
        float2* dst = cand + ((size_t)chunk * QN + tid) * KNN;
#pragma unroll
        for (int c = 0; c < KNN; ++c) dst[c] = make_float2(fs[c], __int_as_float(fi[c]));
    }
}

// Phase B: one wave per query: global top-5 over NC*5 candidates, gather rows,
// exact f32 distances (immune to bf16 ranking jitter), per-query sum.
__global__ void knn_merge_exact(const float* __restrict__ emb, const float* __restrict__ mem,
                                const float2* __restrict__ cand, float* __restrict__ qsum,
                                int Q, int NC) {
    const int q = blockIdx.x;
    const int lane = threadIdx.x;  // 64
    float fs[KNN] = {BIGF, BIGF, BIGF, BIGF, BIGF};
    int   fi[KNN] = {0, 0, 0, 0, 0};
    for (int c = lane; c < NC; c += 64) {
        const float2* p = cand + ((size_t)c * Q + q) * KNN;
#pragma unroll
        for (int k = 0; k < KNN; ++k) {
            float2 e = p[k];
            t5_insert(fs, fi, e.x, __float_as_int(e.y));
        }
    }
    __shared__ float2 ls[64][KNN];
    __shared__ int sel[KNN];
#pragma unroll
    for (int k = 0; k < KNN; ++k) ls[lane][k] = make_float2(fs[k], __int_as_float(fi[k]));
    __syncthreads();
    if (lane == 0) {
        float gs[KNN] = {BIGF, BIGF, BIGF, BIGF, BIGF};
        int   gi[KNN] = {0, 0, 0, 0, 0};
        for (int l = 0; l < 64; ++l)
#pragma unroll
            for (int k = 0; k < KNN; ++k)
                t5_insert(gs, gi, ls[l][k].x, __float_as_int(ls[l][k].y));
#pragma unroll
        for (int k = 0; k < KNN; ++k) sel[k] = gi[k];
    }
    __syncthreads();
    const float4* qp = (const float4*)(emb + (size_t)q * DDIM);
    float4 q0 = qp[lane * 2], q1 = qp[lane * 2 + 1];
    float ssum = 0.f;
    for (int k = 0; k < KNN; ++k) {
        const float4* mp = (const float4*)(mem + (size_t)sel[k] * DDIM);
        float4 m0 = mp[lane * 2], m1 = mp[lane * 2 + 1];
        float d0 = m0.x - q0.x, d1 = m0.y - q0.y, d2 = m0.z - q0.z, d3 = m0.w - q0.w;
        float d4 = m1.x - q1.x, d5 = m1.y - q1.y, d6 = m1.z - q1.z, d7 = m1.w - q1.w;
        float t = d0 * d0 + d1 * d1 + d2 * d2 + d3 * d3 + d4 * d4 + d5 * d5 + d6 * d6 + d7 * d7;
#pragma unroll
        for (int off = 32; off > 0; off >>= 1) t += __shfl_down(t, off);
        if (lane == 0) ssum += sqrtf(t);
    }
    if (lane == 0) qsum[q] = ssum;
}

__global__ void knn_reduce(const float* __restrict__ qsum, float* __restrict__ out, int Q) {
    const int lane = threadIdx.x;
    float v = 0.f;
    for (int i = lane; i < Q; i += 64) v += qsum[i];
#pragma unroll
    for (int off = 32; off > 0; off >>= 1) v += __shfl_down(v, off);
    if (lane == 0) out[0] = v / (float)(Q * KNN);
}

extern "C" void kernel_launch(void* const* d_in, const int* in_sizes, int n_in,
                              void* d_out, int out_size, void* d_ws, size_t ws_size,
                              hipStream_t stream) {
    (void)n_in; (void)out_size; (void)ws_size;
    const float* emb = (const float*)d_in[0];
    const float* mem = (const float*)d_in[1];
    const int Q  = in_sizes[0] / DDIM;       // 256
    const int N  = in_sizes[1] / DDIM;       // 200000
    const int NC = (N + MT - 1) / MT;        // 782

    float2*         cand = (float2*)d_ws;                                        // NC*Q*5*8B ~ 8 MB
    float*          qsum = (float*)((char*)d_ws + (size_t)NC * Q * KNN * 8);     // 1 KB
    unsigned short* qbf  = (unsigned short*)((char*)d_ws + (size_t)NC * Q * KNN * 8 + 1024);

    conv_q<<<(Q * DDIM / 4 + 255) / 256, 256, 0, stream>>>(emb, qbf);
    knn_partial<<<NC, NT, 0, stream>>>(mem, qbf, cand, N);
    knn_merge_exact<<<Q, 64, 0, stream>>>(emb, mem, cand, qsum, Q, NC);
    knn_reduce<<<1, 64, 0, stream>>>(qsum, (float*)d_out, Q);
}